// Round 4
// baseline (7978.819 us; speedup 1.0000x reference)
//
#include <hip/hip_runtime.h>
#include <hip/hip_cooperative_groups.h>
#include <cmath>

namespace cg = cooperative_groups;

constexpr int B = 64, N_SP = 49, ENC = 1024, DEC = 512, EMB = 512, V = 10000;
constexpr int MS = 8, MW = 20;
constexpr int BW = B * MS;        // 512 batched word-rows (s*64+b)
constexpr int XDIM = EMB + ENC;   // 1536
constexpr int GRID = 256;         // persistent kernel workgroups (1/CU guaranteed)
constexpr int NPAD = 10112;       // V padded to 128-multiple for fc MFMA

typedef __attribute__((ext_vector_type(8))) short short8v;   // 8 bf16 in 4 VGPRs
typedef __attribute__((ext_vector_type(4))) float f32x4;

__device__ __forceinline__ unsigned short f2bf(float f) {
    union { float f; unsigned u; } x{f};
    unsigned r = x.u + 0x7FFF + ((x.u >> 16) & 1);   // RNE
    return (unsigned short)(r >> 16);
}

// ---------------- mean over N ----------------
__global__ void mean_kernel(const float* __restrict__ sp, float* __restrict__ g) {
    int b = blockIdx.x;
    for (int c = threadIdx.x; c < ENC; c += blockDim.x) {
        float s = 0.f;
        for (int n = 0; n < N_SP; ++n) s += sp[(size_t)(b * N_SP + n) * ENC + c];
        g[b * ENC + c] = s * (1.0f / 49.0f);
    }
}

// ---------------- generic fp32 GEMM: C = A @ W^T + bias ----------------
template <int BM, int BN, int BK, int TM, int TN, int ACT>
__launch_bounds__(256)
__global__ void gemm_tn(const float* __restrict__ A, int lda,
                        const float* __restrict__ W, int ldw,
                        const float* __restrict__ bias,
                        float* __restrict__ C, int ldc,
                        int M, int N, int K) {
    __shared__ float As[BK][BM + 4];
    __shared__ float Ws[BK][BN + 4];
    const int tid = threadIdx.x;
    const int tx = tid % (BN / TN);
    const int ty = tid / (BN / TN);
    const int m0 = blockIdx.y * BM, n0 = blockIdx.x * BN;
    float acc[TM][TN];
#pragma unroll
    for (int i = 0; i < TM; ++i)
#pragma unroll
        for (int j = 0; j < TN; ++j) acc[i][j] = 0.f;
    constexpr int Q = BK / 4;
    const int arow = tid / Q, akq = (tid % Q) * 4;
    for (int k0 = 0; k0 < K; k0 += BK) {
        float4 av = make_float4(0.f, 0.f, 0.f, 0.f);
        float4 wv = make_float4(0.f, 0.f, 0.f, 0.f);
        int gr = m0 + arow;
        if (gr < M) av = *reinterpret_cast<const float4*>(&A[(size_t)gr * lda + k0 + akq]);
        int gn = n0 + arow;
        if (gn < N) wv = *reinterpret_cast<const float4*>(&W[(size_t)gn * ldw + k0 + akq]);
        __syncthreads();
        As[akq + 0][arow] = av.x; As[akq + 1][arow] = av.y;
        As[akq + 2][arow] = av.z; As[akq + 3][arow] = av.w;
        Ws[akq + 0][arow] = wv.x; Ws[akq + 1][arow] = wv.y;
        Ws[akq + 2][arow] = wv.z; Ws[akq + 3][arow] = wv.w;
        __syncthreads();
#pragma unroll
        for (int kk = 0; kk < BK; ++kk) {
            float a[TM], w[TN];
#pragma unroll
            for (int i = 0; i < TM; ++i) a[i] = As[kk][ty * TM + i];
#pragma unroll
            for (int j = 0; j < TN; ++j) w[j] = Ws[kk][tx * TN + j];
#pragma unroll
            for (int i = 0; i < TM; ++i)
#pragma unroll
                for (int j = 0; j < TN; ++j) acc[i][j] += a[i] * w[j];
        }
        __syncthreads();
    }
#pragma unroll
    for (int i = 0; i < TM; ++i) {
        int r = m0 + ty * TM + i;
        if (r >= M) continue;
#pragma unroll
        for (int j = 0; j < TN; ++j) {
            int n = n0 + tx * TN + j;
            if (n >= N) continue;
            float v = acc[i][j] + bias[n];
            if (ACT == 1) v = tanhf(v);
            C[(size_t)r * ldc + n] = v;
        }
    }
}

// ---------------- GRU gate combine (also fallback path) ----------------
__global__ void gru_combine(const float* __restrict__ gi, const float* __restrict__ gh,
                            const float* __restrict__ hprev, float* __restrict__ hout,
                            float* __restrict__ hout2, unsigned short* __restrict__ hout_bf,
                            int M, int t) {
    int idx = blockIdx.x * blockDim.x + threadIdx.x;
    if (idx >= M * DEC) return;
    int r = idx / DEC, c = idx % DEC;
    size_t g0 = (size_t)r * 3 * DEC + c;
    float ir = gi[g0], iz = gi[g0 + DEC], in_ = gi[g0 + 2 * DEC];
    float hr = gh[g0], hz = gh[g0 + DEC], hn = gh[g0 + 2 * DEC];
    float rr = 1.f / (1.f + expf(-(ir + hr)));
    float zz = 1.f / (1.f + expf(-(iz + hz)));
    float nn = tanhf(in_ + rr * hn);
    float h = (1.f - zz) * nn + zz * hprev[(size_t)r * DEC + c];
    hout[(size_t)r * DEC + c] = h;
    if (hout2) hout2[(size_t)r * DEC + c] = h;
    if (hout_bf) {
        int r2 = ((r >> 6) * MW + t) * 64 + (r & 63);
        hout_bf[(size_t)r2 * DEC + c] = f2bf(h);
    }
}

// ---------------- fallback attention (R1, proven) ----------------
__launch_bounds__(256)
__global__ void attn_kernel(const float* __restrict__ sp, const float* __restrict__ att1,
                            const float* __restrict__ att2, const float* __restrict__ wfull,
                            const float* __restrict__ bfull, const float* __restrict__ embW,
                            const int* __restrict__ tw, float* __restrict__ x, int t) {
    int r = blockIdx.x;
    int s = r >> 6, b = r & 63;
    __shared__ float a2[EMB];
    __shared__ float wf[EMB];
    __shared__ float alpha[64];
    int tid = threadIdx.x;
    for (int c = tid; c < EMB; c += 256) { a2[c] = att2[(size_t)r * EMB + c]; wf[c] = wfull[c]; }
    __syncthreads();
    int wave = tid >> 6, lane = tid & 63;
    for (int n = wave; n < N_SP; n += 4) {
        float acc = 0.f;
        const float* a1p = &att1[(size_t)(b * N_SP + n) * EMB];
        for (int c0 = 0; c0 < EMB; c0 += 64) {
            float v = a1p[c0 + lane] + a2[c0 + lane];
            v = fmaxf(v, 0.f);
            acc += v * wf[c0 + lane];
        }
        for (int m = 32; m; m >>= 1) acc += __shfl_xor(acc, m, 64);
        if (lane == 0) alpha[n] = acc + bfull[0];
    }
    __syncthreads();
    if (tid < 64) {
        float e = (tid < N_SP) ? alpha[tid] : -1e30f;
        float mx = e;
        for (int m = 32; m; m >>= 1) mx = fmaxf(mx, __shfl_xor(mx, m, 64));
        float p = (tid < N_SP) ? expf(e - mx) : 0.f;
        float sum = p;
        for (int m = 32; m; m >>= 1) sum += __shfl_xor(sum, m, 64);
        if (tid < N_SP) alpha[tid] = p / sum;
    }
    __syncthreads();
    for (int c = tid; c < ENC; c += 256) {
        float acc = 0.f;
        const float* spb = &sp[(size_t)b * N_SP * ENC + c];
#pragma unroll 7
        for (int n = 0; n < N_SP; ++n) acc += alpha[n] * spb[(size_t)n * ENC];
        x[(size_t)r * XDIM + EMB + c] = acc;
    }
    int word = (t == 0) ? 1 : tw[b * (MS * MW) + s * MW + (t - 1)];
    for (int c = tid; c < EMB; c += 256) x[(size_t)r * XDIM + c] = embW[(size_t)word * EMB + c];
}

// ---------------- policy / stop heads ----------------
__launch_bounds__(64)
__global__ void policy_kernel(const float* __restrict__ hs_all, const float* __restrict__ pW,
                              const float* __restrict__ pb, const float* __restrict__ sW,
                              const float* __restrict__ sb, float* __restrict__ out) {
    int r = blockIdx.x;
    int s = r >> 6, b = r & 63;
    int lane = threadIdx.x;
    float acc[6] = {0.f, 0.f, 0.f, 0.f, 0.f, 0.f};
    for (int c = lane; c < DEC; c += 64) {
        float h = hs_all[(size_t)r * DEC + c];
#pragma unroll
        for (int j = 0; j < 5; ++j) acc[j] += h * pW[j * DEC + c];
        acc[5] += h * sW[c];
    }
#pragma unroll
    for (int j = 0; j < 6; ++j)
        for (int m = 32; m; m >>= 1) acc[j] += __shfl_xor(acc[j], m, 64);
    if (lane == 0) {
#pragma unroll
        for (int j = 0; j < 5; ++j) out[(b * MS + s) * 5 + j] = acc[j] + pb[j];
        out[B * MS * 5 + b * MS + s] = acc[5] + sb[0];
    }
}

// ---------------- bf16 weight conversion (pad rows >= valid with 0) ----------------
__global__ void conv_w(const float* __restrict__ W, unsigned short* __restrict__ Wb,
                       int rows, int validrows) {
    for (size_t i = (size_t)blockIdx.x * 256 + threadIdx.x; i < (size_t)rows * DEC;
         i += (size_t)gridDim.x * 256) {
        int row = (int)(i >> 9);
        Wb[i] = (row < validrows) ? f2bf(W[i]) : (unsigned short)0;
    }
}

// ================= fc head: bf16 MFMA, C = A @ W^T + bias, scattered store =======
__global__ __launch_bounds__(256)
void fc_mfma(const unsigned short* __restrict__ Ab,   // [10240][512] bf16
             const unsigned short* __restrict__ Wb,   // [NPAD][512] bf16
             const float* __restrict__ bias,          // [V]
             float* __restrict__ out) {
    constexpr int K = 512, BK = 64, RS = 72;          // RS: LDS row stride (bf16), 144B
    __shared__ unsigned short As[128 * RS];
    __shared__ unsigned short Bs[128 * RS];
    const int tid = threadIdx.x;
    const int m0 = blockIdx.y * 128, n0 = blockIdx.x * 128;
    const int lane = tid & 63, wv = tid >> 6;
    const int wm = (wv >> 1) * 64, wn = (wv & 1) * 64;
    f32x4 acc[4][4];
#pragma unroll
    for (int i = 0; i < 4; ++i)
#pragma unroll
        for (int j = 0; j < 4; ++j) acc[i][j] = 0;

    const int l15 = lane & 15, l4 = lane >> 4;
    for (int k0 = 0; k0 < K; k0 += BK) {
        __syncthreads();
#pragma unroll
        for (int q = 0; q < 4; ++q) {
            int unit = q * 256 + tid;
            int row = unit >> 3, u = unit & 7;
            int4 va = *reinterpret_cast<const int4*>(&Ab[(size_t)(m0 + row) * K + k0 + u * 8]);
            *reinterpret_cast<int4*>(&As[row * RS + u * 8]) = va;
            int4 vb = *reinterpret_cast<const int4*>(&Wb[(size_t)(n0 + row) * K + k0 + u * 8]);
            *reinterpret_cast<int4*>(&Bs[row * RS + u * 8]) = vb;
        }
        __syncthreads();
#pragma unroll
        for (int kb = 0; kb < 2; ++kb) {
            short8v af[4], bf[4];
#pragma unroll
            for (int i = 0; i < 4; ++i)
                af[i] = *reinterpret_cast<const short8v*>(
                    &As[(wm + i * 16 + l15) * RS + kb * 32 + l4 * 8]);
#pragma unroll
            for (int j = 0; j < 4; ++j)
                bf[j] = *reinterpret_cast<const short8v*>(
                    &Bs[(wn + j * 16 + l15) * RS + kb * 32 + l4 * 8]);
#pragma unroll
            for (int i = 0; i < 4; ++i)
#pragma unroll
                for (int j = 0; j < 4; ++j)
                    acc[i][j] = __builtin_amdgcn_mfma_f32_16x16x32_bf16(af[i], bf[j], acc[i][j], 0, 0, 0);
        }
    }
    const int crow = l4 * 4;
#pragma unroll
    for (int i = 0; i < 4; ++i) {
        int rgb = m0 + wm + i * 16 + crow;
#pragma unroll
        for (int j = 0; j < 4; ++j) {
            int n_g = n0 + wn + j * 16 + l15;
            if (n_g >= V) continue;
            float bv = bias[n_g];
#pragma unroll
            for (int r = 0; r < 4; ++r) {
                int rg = rgb + r;                         // (s*MW+t)*64+b
                int bb = rg & 63, tt = (rg >> 6) % MW, ss = rg / (64 * MW);
                out[(size_t)((bb * MS + ss) * MW + tt) * V + n_g] = acc[i][j][r] + bv;
            }
        }
    }
}

// ================= persistent cooperative RNN kernel =================
struct RnnParams {
    const float* sp;
    const float* embW;
    const int* tw;
    const float* sWhh; const float* sbhh;
    const float* adW;  const float* adb;
    const float* afW;  const float* afb;
    const float* wWih; const float* wbih;
    const float* wWhh; const float* wbhh;
    const float* att1;
    float* h_s; float* gi_s; float* gh_s; float* h_sall;
    float* att2; float* xbuf; float* gib; float* ghb;
    float* h_w;
    unsigned short* h_all_bf;
};

// 64x64 tile, BK=16, 256 threads, 4x4/thread
__device__ __forceinline__ void gemm_tile64(
    const float* __restrict__ A, int lda, const float* __restrict__ W, int ldw,
    const float* __restrict__ bias, float* __restrict__ C, int ldc,
    int m0, int n0, int K, float* smem) {
    float (*As)[68] = reinterpret_cast<float(*)[68]>(smem);
    float (*Ws)[68] = reinterpret_cast<float(*)[68]>(smem + 16 * 68);
    const int tid = threadIdx.x;
    const int tx = tid & 15, ty = tid >> 4;
    const int lrow = tid >> 2, lkq = (tid & 3) << 2;
    float acc[4][4] = {};
    const float* Ap = A + (size_t)(m0 + lrow) * lda + lkq;
    const float* Wp = W + (size_t)(n0 + lrow) * ldw + lkq;
    for (int k0 = 0; k0 < K; k0 += 16) {
        float4 av = *reinterpret_cast<const float4*>(Ap + k0);
        float4 wv = *reinterpret_cast<const float4*>(Wp + k0);
        __syncthreads();
        As[lkq + 0][lrow] = av.x; As[lkq + 1][lrow] = av.y;
        As[lkq + 2][lrow] = av.z; As[lkq + 3][lrow] = av.w;
        Ws[lkq + 0][lrow] = wv.x; Ws[lkq + 1][lrow] = wv.y;
        Ws[lkq + 2][lrow] = wv.z; Ws[lkq + 3][lrow] = wv.w;
        __syncthreads();
#pragma unroll
        for (int kk = 0; kk < 16; ++kk) {
            float a[4], w[4];
#pragma unroll
            for (int i = 0; i < 4; ++i) a[i] = As[kk][ty * 4 + i];
#pragma unroll
            for (int j = 0; j < 4; ++j) w[j] = Ws[kk][tx * 4 + j];
#pragma unroll
            for (int i = 0; i < 4; ++i)
#pragma unroll
                for (int j = 0; j < 4; ++j) acc[i][j] += a[i] * w[j];
        }
    }
    __syncthreads();
#pragma unroll
    for (int i = 0; i < 4; ++i) {
        float* Cp = C + (size_t)(m0 + ty * 4 + i) * ldc + n0 + tx * 4;
#pragma unroll
        for (int j = 0; j < 4; ++j) Cp[j] = acc[i][j] + bias[n0 + tx * 4 + j];
    }
}

// 64x48 tile, BK=16, 256 threads, 4x3/thread (for 1536-col gi: 8x32=256 jobs)
__device__ __forceinline__ void gemm_tile48(
    const float* __restrict__ A, int lda, const float* __restrict__ W, int ldw,
    const float* __restrict__ bias, float* __restrict__ C, int ldc,
    int m0, int n0, int K, float* smem) {
    float (*As)[68] = reinterpret_cast<float(*)[68]>(smem);
    float (*Ws)[52] = reinterpret_cast<float(*)[52]>(smem + 16 * 68);
    const int tid = threadIdx.x;
    const int tx = tid & 15, ty = tid >> 4;
    const int lrow = tid >> 2, lkq = (tid & 3) << 2;
    const int wrow = tid >> 2;                    // valid for tid<192: rows 0..47
    float acc[4][3] = {};
    const float* Ap = A + (size_t)(m0 + lrow) * lda + lkq;
    const float* Wp = W + (size_t)(n0 + wrow) * ldw + lkq;
    for (int k0 = 0; k0 < K; k0 += 16) {
        float4 av = *reinterpret_cast<const float4*>(Ap + k0);
        float4 wv = make_float4(0.f, 0.f, 0.f, 0.f);
        if (tid < 192) wv = *reinterpret_cast<const float4*>(Wp + k0);
        __syncthreads();
        As[lkq + 0][lrow] = av.x; As[lkq + 1][lrow] = av.y;
        As[lkq + 2][lrow] = av.z; As[lkq + 3][lrow] = av.w;
        if (tid < 192) {
            Ws[lkq + 0][wrow] = wv.x; Ws[lkq + 1][wrow] = wv.y;
            Ws[lkq + 2][wrow] = wv.z; Ws[lkq + 3][wrow] = wv.w;
        }
        __syncthreads();
#pragma unroll
        for (int kk = 0; kk < 16; ++kk) {
            float a[4], w[3];
#pragma unroll
            for (int i = 0; i < 4; ++i) a[i] = As[kk][ty * 4 + i];
#pragma unroll
            for (int j = 0; j < 3; ++j) w[j] = Ws[kk][tx * 3 + j];
#pragma unroll
            for (int i = 0; i < 4; ++i)
#pragma unroll
                for (int j = 0; j < 3; ++j) acc[i][j] += a[i] * w[j];
        }
    }
    __syncthreads();
#pragma unroll
    for (int i = 0; i < 4; ++i) {
        float* Cp = C + (size_t)(m0 + ty * 4 + i) * ldc + n0 + tx * 3;
#pragma unroll
        for (int j = 0; j < 3; ++j) Cp[j] = acc[i][j] + bias[n0 + tx * 3 + j];
    }
}

// attention for one image b: all 8 sentences at once; reads att1/sp once per b
__device__ __forceinline__ void attn_b(const RnnParams& p, int b, int t, float* smem) {
    float* att2s = smem;              // [8][512]
    float* wf = smem + 4096;          // [512]
    float* ee = smem + 4608;          // [8][64] e then alpha
    const int tid = threadIdx.x;
    for (int i = tid; i < 8 * 512; i += 256) {
        int s = i >> 9, c = i & 511;
        att2s[i] = p.att2[(size_t)(s * 64 + b) * EMB + c];
    }
    for (int c = tid; c < 512; c += 256) wf[c] = p.afW[c];
    __syncthreads();
    const int wave = tid >> 6, lane = tid & 63;
    for (int n = wave; n < N_SP; n += 4) {
        const float* a1 = &p.att1[(size_t)(b * N_SP + n) * EMB];
        float accs[8] = {};
        for (int c0 = 0; c0 < 512; c0 += 64) {
            float a1v = a1[c0 + lane];
            float wfv = wf[c0 + lane];
#pragma unroll
            for (int s = 0; s < 8; ++s) {
                float v = a1v + att2s[s * 512 + c0 + lane];
                v = fmaxf(v, 0.f);
                accs[s] += v * wfv;
            }
        }
#pragma unroll
        for (int s = 0; s < 8; ++s) {
            float a = accs[s];
            for (int m = 32; m; m >>= 1) a += __shfl_xor(a, m, 64);
            if (lane == 0) ee[s * 64 + n] = a + p.afb[0];
        }
    }
    __syncthreads();
    for (int s = wave; s < 8; s += 4) {
        float e = (lane < N_SP) ? ee[s * 64 + lane] : -1e30f;
        float mx = e;
        for (int m = 32; m; m >>= 1) mx = fmaxf(mx, __shfl_xor(mx, m, 64));
        float pr = (lane < N_SP) ? expf(e - mx) : 0.f;
        float sm = pr;
        for (int m = 32; m; m >>= 1) sm += __shfl_xor(sm, m, 64);
        if (lane < N_SP) ee[s * 64 + lane] = pr / sm;
    }
    __syncthreads();
    for (int c = tid; c < ENC; c += 256) {
        float acc0[8] = {};
        const float* spb = &p.sp[(size_t)b * N_SP * ENC + c];
        for (int n = 0; n < N_SP; ++n) {
            float v = spb[(size_t)n * ENC];
#pragma unroll
            for (int s = 0; s < 8; ++s) acc0[s] += ee[s * 64 + n] * v;
        }
#pragma unroll
        for (int s = 0; s < 8; ++s)
            p.xbuf[(size_t)(s * 64 + b) * XDIM + EMB + c] = acc0[s];
    }
    for (int i = tid; i < 8 * 512; i += 256) {
        int s = i >> 9, c = i & 511;
        int word = (t == 0) ? 1 : p.tw[b * (MS * MW) + s * MW + (t - 1)];
        p.xbuf[(size_t)(s * 64 + b) * XDIM + c] = p.embW[(size_t)word * EMB + c];
    }
    __syncthreads();
}

__global__ __launch_bounds__(256)
void rnn_persistent(RnnParams p) {
    cg::grid_group grid = cg::this_grid();
    __shared__ float smem[5120];
    const int wg = blockIdx.x;
    const int tid = threadIdx.x;

    // ---- sentence GRU: 8 sequential steps ----
    for (int i = 0; i < MS; ++i) {
        if (wg < 24)
            gemm_tile64(p.h_s, DEC, p.sWhh, DEC, p.sbhh, p.gh_s, 3 * DEC, 0, wg * 64, DEC, smem);
        grid.sync();
        for (int idx = wg * 256 + tid; idx < B * DEC; idx += GRID * 256) {
            int c = idx & 511, r = idx >> 9;
            size_t g0 = (size_t)r * 3 * DEC + c;
            float ir = p.gi_s[g0], iz = p.gi_s[g0 + DEC], in_ = p.gi_s[g0 + 2 * DEC];
            float hr = p.gh_s[g0], hz = p.gh_s[g0 + DEC], hn = p.gh_s[g0 + 2 * DEC];
            float rr = 1.f / (1.f + expf(-(ir + hr)));
            float zz = 1.f / (1.f + expf(-(iz + hz)));
            float nn = tanhf(in_ + rr * hn);
            float h = (1.f - zz) * nn + zz * p.h_s[idx];
            p.h_s[idx] = h;
            p.h_sall[(size_t)i * B * DEC + idx] = h;
            p.h_w[(size_t)i * B * DEC + idx] = h;
        }
        grid.sync();
    }

    // ---- word GRU: 20 sequential steps, 512 batched rows ----
    for (int t = 0; t < MW; ++t) {
        // Phase A: 256 jobs = 64 att2 tiles + 192 gh tiles (both K=512)
        if (wg < 64)
            gemm_tile64(p.h_w, DEC, p.adW, DEC, p.adb, p.att2, EMB,
                        (wg >> 3) * 64, (wg & 7) * 64, DEC, smem);
        else {
            int j = wg - 64;
            gemm_tile64(p.h_w, DEC, p.wWhh, DEC, p.wbhh, p.ghb, 3 * DEC,
                        (j / 24) * 64, (j % 24) * 64, DEC, smem);
        }
        grid.sync();
        // Phase B: attention per image b (64 wgs)
        if (wg < 64) attn_b(p, wg, t, smem);
        grid.sync();
        // Phase C: gi = x @ wWih^T, 256 jobs of 64x48, K=1536
        gemm_tile48(p.xbuf, XDIM, p.wWih, XDIM, p.wbih, p.gib, 3 * DEC,
                    (wg >> 5) * 64, (wg & 31) * 48, XDIM, smem);
        grid.sync();
        // Phase D: GRU combine -> h_w (fp32), h_all (bf16)
        for (int idx = wg * 256 + tid; idx < BW * DEC; idx += GRID * 256) {
            int c = idx & 511, r = idx >> 9;
            size_t g0 = (size_t)r * 3 * DEC + c;
            float ir = p.gib[g0], iz = p.gib[g0 + DEC], in_ = p.gib[g0 + 2 * DEC];
            float hr = p.ghb[g0], hz = p.ghb[g0 + DEC], hn = p.ghb[g0 + 2 * DEC];
            float rr = 1.f / (1.f + expf(-(ir + hr)));
            float zz = 1.f / (1.f + expf(-(iz + hz)));
            float nn = tanhf(in_ + rr * hn);
            float h = (1.f - zz) * nn + zz * p.h_w[idx];
            p.h_w[idx] = h;
            int r2 = ((r >> 6) * MW + t) * 64 + (r & 63);
            p.h_all_bf[(size_t)r2 * DEC + c] = f2bf(h);
        }
        grid.sync();
    }
}

extern "C" void kernel_launch(void* const* d_in, const int* in_sizes, int n_in,
                              void* d_out, int out_size, void* d_ws, size_t ws_size,
                              hipStream_t stream) {
    const float* sp   = (const float*)d_in[0];
    const int*   tw   = (const int*)d_in[1];
    const float* embW = (const float*)d_in[2];
    const float* sWih = (const float*)d_in[3];
    const float* sWhh = (const float*)d_in[4];
    const float* sbih = (const float*)d_in[5];
    const float* sbhh = (const float*)d_in[6];
    const float* pW   = (const float*)d_in[7];
    const float* pb   = (const float*)d_in[8];
    const float* stW  = (const float*)d_in[9];
    const float* stb  = (const float*)d_in[10];
    const float* aeW  = (const float*)d_in[11];
    const float* aeb  = (const float*)d_in[12];
    const float* adW  = (const float*)d_in[13];
    const float* adb  = (const float*)d_in[14];
    const float* afW  = (const float*)d_in[15];
    const float* afb  = (const float*)d_in[16];
    const float* wWih = (const float*)d_in[17];
    const float* wWhh = (const float*)d_in[18];
    const float* wbih = (const float*)d_in[19];
    const float* wbhh = (const float*)d_in[20];
    const float* fcW  = (const float*)d_in[21];
    const float* fcb  = (const float*)d_in[22];
    const float* iW   = (const float*)d_in[23];
    const float* ib   = (const float*)d_in[24];
    float* out = (float*)d_out;

    float* w = (float*)d_ws;
    float* g      = w; w += B * ENC;
    float* att1   = w; w += (size_t)B * N_SP * EMB;
    float* h_s    = w; w += B * DEC;
    float* gi_s   = w; w += B * 3 * DEC;
    float* gh_s   = w; w += B * 3 * DEC;
    float* h_sall = w; w += MS * B * DEC;
    float* xbuf   = w; w += (size_t)BW * XDIM;
    float* att2   = w; w += (size_t)BW * EMB;
    float* gib    = w; w += (size_t)BW * 3 * DEC;
    float* ghb    = w; w += (size_t)BW * 3 * DEC;
    float* h_w    = w; w += (size_t)BW * DEC;
    unsigned short* h_all_bf = (unsigned short*)w;     // [10240][512] bf16
    unsigned short* fcW_bf = h_all_bf + (size_t)MS * MW * B * DEC;   // [NPAD][512]

    // Phase 0: one-shot precompute
    mean_kernel<<<B, 256, 0, stream>>>(sp, g);
    gemm_tn<64, 64, 16, 4, 4, 0><<<dim3(512 / 64, (B * N_SP) / 64), 256, 0, stream>>>(
        sp, ENC, aeW, ENC, aeb, att1, EMB, B * N_SP, EMB, ENC);
    gemm_tn<64, 64, 16, 4, 4, 1><<<dim3(512 / 64, 1), 256, 0, stream>>>(
        g, ENC, iW, ENC, ib, h_s, DEC, B, DEC, ENC);
    gemm_tn<64, 64, 16, 4, 4, 0><<<dim3(1536 / 64, 1), 256, 0, stream>>>(
        g, ENC, sWih, ENC, sbih, gi_s, 3 * DEC, B, 3 * DEC, ENC);
    conv_w<<<1024, 256, 0, stream>>>(fcW, fcW_bf, NPAD, V);

    // Phase 1+2: persistent cooperative kernel
    RnnParams prm;
    prm.sp = sp; prm.embW = embW; prm.tw = tw;
    prm.sWhh = sWhh; prm.sbhh = sbhh;
    prm.adW = adW; prm.adb = adb; prm.afW = afW; prm.afb = afb;
    prm.wWih = wWih; prm.wbih = wbih; prm.wWhh = wWhh; prm.wbhh = wbhh;
    prm.att1 = att1;
    prm.h_s = h_s; prm.gi_s = gi_s; prm.gh_s = gh_s; prm.h_sall = h_sall;
    prm.att2 = att2; prm.xbuf = xbuf; prm.gib = gib; prm.ghb = ghb;
    prm.h_w = h_w; prm.h_all_bf = h_all_bf;
    void* kargs[] = { (void*)&prm };
    hipError_t cerr = hipLaunchCooperativeKernel(
        reinterpret_cast<const void*>(&rnn_persistent), dim3(GRID), dim3(256), kargs, 0, stream);
    if (cerr != hipSuccess) {
        // -------- fallback: proven discrete-kernel path (R1) --------
        for (int i = 0; i < MS; ++i) {
            gemm_tn<64, 64, 16, 4, 4, 0><<<dim3(1536 / 64, 1), 256, 0, stream>>>(
                h_s, DEC, sWhh, DEC, sbhh, gh_s, 3 * DEC, B, 3 * DEC, DEC);
            gru_combine<<<(B * DEC + 255) / 256, 256, 0, stream>>>(
                gi_s, gh_s, h_s, h_s, h_sall + (size_t)i * B * DEC, nullptr, B, 0);
        }
        hipMemcpyAsync(h_w, h_sall, (size_t)BW * DEC * sizeof(float),
                       hipMemcpyDeviceToDevice, stream);
        for (int t = 0; t < MW; ++t) {
            gemm_tn<64, 64, 16, 4, 4, 0><<<dim3(512 / 64, 512 / 64), 256, 0, stream>>>(
                h_w, DEC, adW, DEC, adb, att2, EMB, BW, EMB, DEC);
            attn_kernel<<<BW, 256, 0, stream>>>(sp, att1, att2, afW, afb, embW, tw, xbuf, t);
            gemm_tn<64, 64, 16, 4, 4, 0><<<dim3(1536 / 64, 512 / 64), 256, 0, stream>>>(
                xbuf, XDIM, wWih, XDIM, wbih, gib, 3 * DEC, BW, 3 * DEC, XDIM);
            gemm_tn<64, 64, 16, 4, 4, 0><<<dim3(1536 / 64, 512 / 64), 256, 0, stream>>>(
                h_w, DEC, wWhh, DEC, wbhh, ghb, 3 * DEC, BW, 3 * DEC, DEC);
            gru_combine<<<(BW * DEC + 255) / 256, 256, 0, stream>>>(
                gib, ghb, h_w, h_w, nullptr, h_all_bf, BW, t);
        }
    }

    // Phase 3: heads
    policy_kernel<<<BW, 64, 0, stream>>>(h_sall, pW, pb, stW, stb, out);
    fc_mfma<<<dim3(NPAD / 128, (MS * MW * B) / 128), 256, 0, stream>>>(
        h_all_bf, fcW_bf, fcb, out + B * MS * 5 + B * MS);
}

// Round 8
// 6298.142 us; speedup vs baseline: 1.2669x; 1.2669x over previous
//
#include <hip/hip_runtime.h>
#include <hip/hip_cooperative_groups.h>
#include <cmath>

namespace cg = cooperative_groups;

constexpr int B = 64, N_SP = 49, ENC = 1024, DEC = 512, EMB = 512, V = 10000;
constexpr int MS = 8, MW = 20;
constexpr int BW = B * MS;        // 512 batched word-rows (s*64+b)
constexpr int XDIM = EMB + ENC;   // 1536
constexpr int GRIDW = 512;        // word-loop coop wgs (2/CU at <=128 VGPR)
constexpr int NPAD = 10112;       // V padded to 128-multiple for fc MFMA

typedef __attribute__((ext_vector_type(8))) short short8v;
typedef __attribute__((ext_vector_type(4))) float f32x4;

__device__ __forceinline__ unsigned short f2bf(float f) {
    union { float f; unsigned u; } x{f};
    unsigned r = x.u + 0x7FFF + ((x.u >> 16) & 1);
    return (unsigned short)(r >> 16);
}
__device__ __forceinline__ float bf2f(unsigned short u) {
    union { unsigned u; float f; } x; x.u = ((unsigned)u) << 16; return x.f;
}
__device__ __forceinline__ float sigm(float x) { return 1.f / (1.f + expf(-x)); }

// ---------------- mean over N ----------------
__global__ void mean_kernel(const float* __restrict__ sp, float* __restrict__ g) {
    int b = blockIdx.x;
    for (int c = threadIdx.x; c < ENC; c += blockDim.x) {
        float s = 0.f;
        for (int n = 0; n < N_SP; ++n) s += sp[(size_t)(b * N_SP + n) * ENC + c];
        g[b * ENC + c] = s * (1.0f / 49.0f);
    }
}

// ---------------- generic fp32 GEMM (pre + fallback) ----------------
template <int BM, int BN, int BK, int TM, int TN, int ACT>
__launch_bounds__(256)
__global__ void gemm_tn(const float* __restrict__ A, int lda,
                        const float* __restrict__ W, int ldw,
                        const float* __restrict__ bias,
                        float* __restrict__ C, int ldc,
                        int M, int N, int K) {
    __shared__ float As[BK][BM + 4];
    __shared__ float Ws[BK][BN + 4];
    const int tid = threadIdx.x;
    const int tx = tid % (BN / TN);
    const int ty = tid / (BN / TN);
    const int m0 = blockIdx.y * BM, n0 = blockIdx.x * BN;
    float acc[TM][TN];
#pragma unroll
    for (int i = 0; i < TM; ++i)
#pragma unroll
        for (int j = 0; j < TN; ++j) acc[i][j] = 0.f;
    constexpr int Q = BK / 4;
    const int arow = tid / Q, akq = (tid % Q) * 4;
    for (int k0 = 0; k0 < K; k0 += BK) {
        float4 av = make_float4(0.f, 0.f, 0.f, 0.f);
        float4 wv = make_float4(0.f, 0.f, 0.f, 0.f);
        int gr = m0 + arow;
        if (gr < M) av = *reinterpret_cast<const float4*>(&A[(size_t)gr * lda + k0 + akq]);
        int gn = n0 + arow;
        if (gn < N) wv = *reinterpret_cast<const float4*>(&W[(size_t)gn * ldw + k0 + akq]);
        __syncthreads();
        As[akq + 0][arow] = av.x; As[akq + 1][arow] = av.y;
        As[akq + 2][arow] = av.z; As[akq + 3][arow] = av.w;
        Ws[akq + 0][arow] = wv.x; Ws[akq + 1][arow] = wv.y;
        Ws[akq + 2][arow] = wv.z; Ws[akq + 3][arow] = wv.w;
        __syncthreads();
#pragma unroll
        for (int kk = 0; kk < BK; ++kk) {
            float a[TM], w[TN];
#pragma unroll
            for (int i = 0; i < TM; ++i) a[i] = As[kk][ty * TM + i];
#pragma unroll
            for (int j = 0; j < TN; ++j) w[j] = Ws[kk][tx * TN + j];
#pragma unroll
            for (int i = 0; i < TM; ++i)
#pragma unroll
                for (int j = 0; j < TN; ++j) acc[i][j] += a[i] * w[j];
        }
        __syncthreads();
    }
#pragma unroll
    for (int i = 0; i < TM; ++i) {
        int r = m0 + ty * TM + i;
        if (r >= M) continue;
#pragma unroll
        for (int j = 0; j < TN; ++j) {
            int n = n0 + tx * TN + j;
            if (n >= N) continue;
            float v = acc[i][j] + bias[n];
            if (ACT == 1) v = tanhf(v);
            C[(size_t)r * ldc + n] = v;
        }
    }
}

// ---------------- fallback GRU combine ----------------
__global__ void gru_combine(const float* __restrict__ gi, const float* __restrict__ gh,
                            const float* __restrict__ hprev, float* __restrict__ hout,
                            unsigned short* __restrict__ hout_bf, int M, int t) {
    int idx = blockIdx.x * blockDim.x + threadIdx.x;
    if (idx >= M * DEC) return;
    int r = idx / DEC, c = idx % DEC;
    size_t g0 = (size_t)r * 3 * DEC + c;
    float rr = sigm(gi[g0] + gh[g0]);
    float zz = sigm(gi[g0 + DEC] + gh[g0 + DEC]);
    float nn = tanhf(gi[g0 + 2 * DEC] + rr * gh[g0 + 2 * DEC]);
    float h = (1.f - zz) * nn + zz * hprev[(size_t)r * DEC + c];
    hout[(size_t)r * DEC + c] = h;
    if (hout_bf) {
        int r2 = ((r >> 6) * MW + t) * 64 + (r & 63);
        hout_bf[(size_t)r2 * DEC + c] = f2bf(h);
    }
}

// ---------------- fallback attention (R1, proven) ----------------
__launch_bounds__(256)
__global__ void attn_kernel(const float* __restrict__ sp, const float* __restrict__ att1,
                            const float* __restrict__ att2, const float* __restrict__ wfull,
                            const float* __restrict__ bfull, const float* __restrict__ embW,
                            const int* __restrict__ tw, float* __restrict__ x, int t) {
    int r = blockIdx.x;
    int s = r >> 6, b = r & 63;
    __shared__ float a2[EMB];
    __shared__ float wf[EMB];
    __shared__ float alpha[64];
    int tid = threadIdx.x;
    for (int c = tid; c < EMB; c += 256) { a2[c] = att2[(size_t)r * EMB + c]; wf[c] = wfull[c]; }
    __syncthreads();
    int wave = tid >> 6, lane = tid & 63;
    for (int n = wave; n < N_SP; n += 4) {
        float acc = 0.f;
        const float* a1p = &att1[(size_t)(b * N_SP + n) * EMB];
        for (int c0 = 0; c0 < EMB; c0 += 64) {
            float v = a1p[c0 + lane] + a2[c0 + lane];
            v = fmaxf(v, 0.f);
            acc += v * wf[c0 + lane];
        }
        for (int m = 32; m; m >>= 1) acc += __shfl_xor(acc, m, 64);
        if (lane == 0) alpha[n] = acc + bfull[0];
    }
    __syncthreads();
    if (tid < 64) {
        float e = (tid < N_SP) ? alpha[tid] : -1e30f;
        float mx = e;
        for (int m = 32; m; m >>= 1) mx = fmaxf(mx, __shfl_xor(mx, m, 64));
        float p = (tid < N_SP) ? expf(e - mx) : 0.f;
        float sum = p;
        for (int m = 32; m; m >>= 1) sum += __shfl_xor(sum, m, 64);
        if (tid < N_SP) alpha[tid] = p / sum;
    }
    __syncthreads();
    for (int c = tid; c < ENC; c += 256) {
        float acc = 0.f;
        const float* spb = &sp[(size_t)b * N_SP * ENC + c];
#pragma unroll 7
        for (int n = 0; n < N_SP; ++n) acc += alpha[n] * spb[(size_t)n * ENC];
        x[(size_t)r * XDIM + EMB + c] = acc;
    }
    int word = (t == 0) ? 1 : tw[b * (MS * MW) + s * MW + (t - 1)];
    for (int c = tid; c < EMB; c += 256) x[(size_t)r * XDIM + c] = embW[(size_t)word * EMB + c];
}

// ---------------- policy / stop heads ----------------
__launch_bounds__(64)
__global__ void policy_kernel(const float* __restrict__ hs_all, const float* __restrict__ pW,
                              const float* __restrict__ pb, const float* __restrict__ sW,
                              const float* __restrict__ sb, float* __restrict__ out) {
    int r = blockIdx.x;
    int s = r >> 6, b = r & 63;
    int lane = threadIdx.x;
    float acc[6] = {0.f, 0.f, 0.f, 0.f, 0.f, 0.f};
    for (int c = lane; c < DEC; c += 64) {
        float h = hs_all[(size_t)r * DEC + c];
#pragma unroll
        for (int j = 0; j < 5; ++j) acc[j] += h * pW[j * DEC + c];
        acc[5] += h * sW[c];
    }
#pragma unroll
    for (int j = 0; j < 6; ++j)
        for (int m = 32; m; m >>= 1) acc[j] += __shfl_xor(acc[j], m, 64);
    if (lane == 0) {
#pragma unroll
        for (int j = 0; j < 5; ++j) out[(b * MS + s) * 5 + j] = acc[j] + pb[j];
        out[B * MS * 5 + b * MS + s] = acc[5] + sb[0];
    }
}

// ---------------- conversions ----------------
__global__ void conv_w(const float* __restrict__ W, unsigned short* __restrict__ Wb,
                       int rows, int validrows) {
    for (size_t i = (size_t)blockIdx.x * 256 + threadIdx.x; i < (size_t)rows * DEC;
         i += (size_t)gridDim.x * 256) {
        int row = (int)(i >> 9);
        Wb[i] = (row < validrows) ? f2bf(W[i]) : (unsigned short)0;
    }
}
__global__ void conv_plain(const float* __restrict__ src, unsigned short* __restrict__ dst, size_t n) {
    for (size_t i = (size_t)blockIdx.x * 256 + threadIdx.x; i < n; i += (size_t)gridDim.x * 256)
        dst[i] = f2bf(src[i]);
}
// pack wWih[:, c0:c0+cnt] -> [1536, cnt] bf16
__global__ void conv_slice(const float* __restrict__ W, unsigned short* __restrict__ out,
                           int c0, int cnt) {
    for (int i = blockIdx.x * 256 + threadIdx.x; i < 1536 * cnt; i += gridDim.x * 256) {
        int r = i / cnt, c = i - r * cnt;
        out[i] = f2bf(W[(size_t)r * XDIM + c0 + c]);
    }
}

// ================= generic bf16 MFMA GEMM: Cb[M,N] = Ab[M,K] @ Bb[N,K]^T =======
__global__ __launch_bounds__(256)
void gemm_bf16(const unsigned short* __restrict__ Ab, const unsigned short* __restrict__ Bb,
               unsigned short* __restrict__ Cb, int M, int N, int K) {
    constexpr int RS = 72;
    __shared__ unsigned short As[128 * RS];
    __shared__ unsigned short Bs[128 * RS];
    const int tid = threadIdx.x;
    const int m0 = blockIdx.y * 128, n0 = blockIdx.x * 128;
    const int lane = tid & 63, wv = tid >> 6;
    const int wm = (wv >> 1) * 64, wn = (wv & 1) * 64;
    f32x4 acc[4][4];
#pragma unroll
    for (int i = 0; i < 4; ++i)
#pragma unroll
        for (int j = 0; j < 4; ++j) acc[i][j] = 0;
    const int l15 = lane & 15, l4 = lane >> 4;
    for (int k0 = 0; k0 < K; k0 += 64) {
        __syncthreads();
#pragma unroll
        for (int q = 0; q < 4; ++q) {
            int unit = q * 256 + tid;
            int row = unit >> 3, u = unit & 7;
            int4 va = make_int4(0, 0, 0, 0);
            if (m0 + row < M)
                va = *reinterpret_cast<const int4*>(&Ab[(size_t)(m0 + row) * K + k0 + u * 8]);
            *reinterpret_cast<int4*>(&As[row * RS + u * 8]) = va;
            int4 vb = *reinterpret_cast<const int4*>(&Bb[(size_t)(n0 + row) * K + k0 + u * 8]);
            *reinterpret_cast<int4*>(&Bs[row * RS + u * 8]) = vb;
        }
        __syncthreads();
#pragma unroll
        for (int kb = 0; kb < 2; ++kb) {
            short8v af[4], bf[4];
#pragma unroll
            for (int i = 0; i < 4; ++i)
                af[i] = *reinterpret_cast<const short8v*>(&As[(wm + i * 16 + l15) * RS + kb * 32 + l4 * 8]);
#pragma unroll
            for (int j = 0; j < 4; ++j)
                bf[j] = *reinterpret_cast<const short8v*>(&Bs[(wn + j * 16 + l15) * RS + kb * 32 + l4 * 8]);
#pragma unroll
            for (int i = 0; i < 4; ++i)
#pragma unroll
                for (int j = 0; j < 4; ++j)
                    acc[i][j] = __builtin_amdgcn_mfma_f32_16x16x32_bf16(af[i], bf[j], acc[i][j], 0, 0, 0);
        }
    }
    const int crow = l4 * 4;
#pragma unroll
    for (int i = 0; i < 4; ++i) {
#pragma unroll
        for (int j = 0; j < 4; ++j) {
            int n_g = n0 + wn + j * 16 + l15;
#pragma unroll
            for (int r = 0; r < 4; ++r) {
                int rg = m0 + wm + i * 16 + crow + r;
                if (rg < M) Cb[(size_t)rg * N + n_g] = f2bf(acc[i][j][r]);
            }
        }
    }
}

// ================= fc head: bf16 MFMA with scatter (proven R4) =======
__global__ __launch_bounds__(256)
void fc_mfma(const unsigned short* __restrict__ Ab, const unsigned short* __restrict__ Wb,
             const float* __restrict__ bias, float* __restrict__ out) {
    constexpr int K = 512, BK = 64, RS = 72;
    __shared__ unsigned short As[128 * RS];
    __shared__ unsigned short Bs[128 * RS];
    const int tid = threadIdx.x;
    const int m0 = blockIdx.y * 128, n0 = blockIdx.x * 128;
    const int lane = tid & 63, wv = tid >> 6;
    const int wm = (wv >> 1) * 64, wn = (wv & 1) * 64;
    f32x4 acc[4][4];
#pragma unroll
    for (int i = 0; i < 4; ++i)
#pragma unroll
        for (int j = 0; j < 4; ++j) acc[i][j] = 0;
    const int l15 = lane & 15, l4 = lane >> 4;
    for (int k0 = 0; k0 < K; k0 += BK) {
        __syncthreads();
#pragma unroll
        for (int q = 0; q < 4; ++q) {
            int unit = q * 256 + tid;
            int row = unit >> 3, u = unit & 7;
            int4 va = *reinterpret_cast<const int4*>(&Ab[(size_t)(m0 + row) * K + k0 + u * 8]);
            *reinterpret_cast<int4*>(&As[row * RS + u * 8]) = va;
            int4 vb = *reinterpret_cast<const int4*>(&Wb[(size_t)(n0 + row) * K + k0 + u * 8]);
            *reinterpret_cast<int4*>(&Bs[row * RS + u * 8]) = vb;
        }
        __syncthreads();
#pragma unroll
        for (int kb = 0; kb < 2; ++kb) {
            short8v af[4], bf[4];
#pragma unroll
            for (int i = 0; i < 4; ++i)
                af[i] = *reinterpret_cast<const short8v*>(&As[(wm + i * 16 + l15) * RS + kb * 32 + l4 * 8]);
#pragma unroll
            for (int j = 0; j < 4; ++j)
                bf[j] = *reinterpret_cast<const short8v*>(&Bs[(wn + j * 16 + l15) * RS + kb * 32 + l4 * 8]);
#pragma unroll
            for (int i = 0; i < 4; ++i)
#pragma unroll
                for (int j = 0; j < 4; ++j)
                    acc[i][j] = __builtin_amdgcn_mfma_f32_16x16x32_bf16(af[i], bf[j], acc[i][j], 0, 0, 0);
        }
    }
    const int crow = l4 * 4;
#pragma unroll
    for (int i = 0; i < 4; ++i) {
        int rgb = m0 + wm + i * 16 + crow;
#pragma unroll
        for (int j = 0; j < 4; ++j) {
            int n_g = n0 + wn + j * 16 + l15;
            if (n_g >= V) continue;
            float bv = bias[n_g];
#pragma unroll
            for (int r = 0; r < 4; ++r) {
                int rg = rgb + r;
                int bb = rg & 63, tt = (rg >> 6) % MW, ss = rg / (64 * MW);
                out[(size_t)((bb * MS + ss) * MW + tt) * V + n_g] = acc[i][j][r] + bv;
            }
        }
    }
}

// ================= sentence GRU: 64 blocks, one image each, sync-free =========
__global__ __launch_bounds__(256)
void sent_gru(const float* __restrict__ h0, const float* __restrict__ gi_s,
              const float* __restrict__ sWhh, const float* __restrict__ sbhh,
              float* __restrict__ h_sall, float* __restrict__ h_w) {
    const int b = blockIdx.x, tid = threadIdx.x;
    __shared__ float h[512];
    h[tid] = h0[b * 512 + tid];
    h[tid + 256] = h0[b * 512 + tid + 256];
    __syncthreads();
    for (int i = 0; i < MS; ++i) {
        float gh[6];
#pragma unroll
        for (int j = 0; j < 6; ++j) {
            int n = tid + (j << 8);
            const float4* wr = reinterpret_cast<const float4*>(&sWhh[(size_t)n * 512]);
            float acc = 0.f;
#pragma unroll 4
            for (int k = 0; k < 128; ++k) {
                float4 wv = wr[k];
                float4 hv = *reinterpret_cast<const float4*>(&h[k * 4]);
                acc = fmaf(wv.x, hv.x, acc); acc = fmaf(wv.y, hv.y, acc);
                acc = fmaf(wv.z, hv.z, acc); acc = fmaf(wv.w, hv.w, acc);
            }
            gh[j] = acc + sbhh[n];
        }
        const float* gib_ = &gi_s[(size_t)b * 1536];
        float gi0 = gib_[tid],       gi1 = gib_[tid + 256];
        float gi2 = gib_[tid + 512], gi3 = gib_[tid + 768];
        float gi4 = gib_[tid + 1024], gi5 = gib_[tid + 1280];
        __syncthreads();                     // all LDS h reads complete
        float hp0 = h[tid], hp1 = h[tid + 256];
        float r0 = sigm(gi0 + gh[0]), z0 = sigm(gi2 + gh[2]);
        float n0_ = tanhf(gi4 + r0 * gh[4]);
        float hn0 = (1.f - z0) * n0_ + z0 * hp0;
        float r1 = sigm(gi1 + gh[1]), z1 = sigm(gi3 + gh[3]);
        float n1_ = tanhf(gi5 + r1 * gh[5]);
        float hn1 = (1.f - z1) * n1_ + z1 * hp1;
        h[tid] = hn0; h[tid + 256] = hn1;
        size_t ro = (size_t)(i * 64 + b) * 512;
        h_sall[ro + tid] = hn0; h_sall[ro + tid + 256] = hn1;
        h_w[ro + tid] = hn0;    h_w[ro + tid + 256] = hn1;
        __syncthreads();
    }
}

// ================= word-loop persistent cooperative kernel =================
struct Wp {
    const float* adW;  const float* adb;
    const float* wWhh; const float* wbhh;
    const float* wbih;
    const float* att1; const float* afW; const float* afb;
    const int* tw;
    const unsigned short* E1_bf; const unsigned short* P_bf;
    float* h_w; float* att2; float* ghb; float* gib;
    unsigned short* h_all_bf;
};

// 64x32 fp32 tile, 256 thr, acc 2x4
__device__ __forceinline__ void gemm_tile_64x32(
    const float* __restrict__ A, int lda, const float* __restrict__ W, int ldw,
    const float* __restrict__ bias, float* __restrict__ C, int ldc,
    int m0, int n0, int K, float* smem) {
    float (*As)[68] = reinterpret_cast<float(*)[68]>(smem);
    float (*Ws)[36] = reinterpret_cast<float(*)[36]>(smem + 16 * 68);
    const int tid = threadIdx.x;
    const int tx = tid & 7, ty = tid >> 3;           // 8 col-groups x 32 row-groups
    const int arow = tid >> 2, akq = (tid & 3) << 2; // 64 rows x 4 quads
    const int wrow = tid >> 3, wkp = (tid & 7) << 1; // 32 rows x 8 pairs
    float acc[2][4] = {};
    const float* Ap = A + (size_t)(m0 + arow) * lda + akq;
    const float* Wpt = W + (size_t)(n0 + wrow) * ldw + wkp;
    for (int k0 = 0; k0 < K; k0 += 16) {
        float4 av = *reinterpret_cast<const float4*>(Ap + k0);
        float2 wv = *reinterpret_cast<const float2*>(Wpt + k0);
        __syncthreads();
        As[akq + 0][arow] = av.x; As[akq + 1][arow] = av.y;
        As[akq + 2][arow] = av.z; As[akq + 3][arow] = av.w;
        Ws[wkp + 0][wrow] = wv.x; Ws[wkp + 1][wrow] = wv.y;
        __syncthreads();
#pragma unroll
        for (int kk = 0; kk < 16; ++kk) {
            float a[2], w[4];
#pragma unroll
            for (int i = 0; i < 2; ++i) a[i] = As[kk][ty * 2 + i];
#pragma unroll
            for (int j = 0; j < 4; ++j) w[j] = Ws[kk][tx * 4 + j];
#pragma unroll
            for (int i = 0; i < 2; ++i)
#pragma unroll
                for (int j = 0; j < 4; ++j) acc[i][j] = fmaf(a[i], w[j], acc[i][j]);
        }
    }
    __syncthreads();
#pragma unroll
    for (int i = 0; i < 2; ++i) {
        float* Cp = C + (size_t)(m0 + ty * 2 + i) * ldc + n0 + tx * 4;
#pragma unroll
        for (int j = 0; j < 4; ++j) Cp[j] = acc[i][j] + bias[n0 + tx * 4 + j];
    }
}

// attention + alphaP + E1 + combine for one image b (one wg)
__device__ __forceinline__ void word_phaseB(const Wp& p, int b, int t, float* smem, int* warr) {
    float* att2s = smem;            // [8][512]
    float* wf    = smem + 4096;     // [512]
    float* ee    = smem + 4608;     // [8][64]
    const int tid = threadIdx.x;
    for (int i = tid; i < 8 * 512; i += 256) {
        int s = i >> 9, c = i & 511;
        att2s[i] = p.att2[(size_t)(s * 64 + b) * EMB + c];
    }
    for (int c = tid; c < 512; c += 256) wf[c] = p.afW[c];
    if (tid < 8) warr[tid] = (t == 0) ? 1 : p.tw[b * (MS * MW) + tid * MW + (t - 1)];
    __syncthreads();
    const int wave = tid >> 6, lane = tid & 63;
    const float afb0 = p.afb[0];
    for (int n = wave; n < N_SP; n += 4) {
        const float* a1 = p.att1 + (size_t)(b * N_SP + n) * EMB;
        float accs[8] = {};
        for (int c0 = 0; c0 < 512; c0 += 64) {
            float a1v = a1[c0 + lane], wv = wf[c0 + lane];
#pragma unroll
            for (int s = 0; s < 8; ++s) {
                float v = fmaxf(a1v + att2s[s * 512 + c0 + lane], 0.f);
                accs[s] = fmaf(v, wv, accs[s]);
            }
        }
#pragma unroll
        for (int s = 0; s < 8; ++s) {
            float a = accs[s];
            for (int m = 32; m; m >>= 1) a += __shfl_xor(a, m, 64);
            if (lane == 0) ee[s * 64 + n] = a + afb0;
        }
    }
    __syncthreads();
    for (int s = wave; s < 8; s += 4) {
        float e = (lane < N_SP) ? ee[s * 64 + lane] : -1e30f;
        float mx = e;
        for (int m = 32; m; m >>= 1) mx = fmaxf(mx, __shfl_xor(mx, m, 64));
        float pr = (lane < N_SP) ? expf(e - mx) : 0.f;
        float sm = pr;
        for (int m = 32; m; m >>= 1) sm += __shfl_xor(sm, m, 64);
        if (lane < N_SP) ee[s * 64 + lane] = pr / sm;
    }
    __syncthreads();
    // gi[s][c0..c0+5] = E1[word_s] + sum_n alpha * P[b,n] + b_ih
    const int c0 = tid * 6;
    float acc[8][6] = {};
    for (int n = 0; n < N_SP; ++n) {
        const unsigned short* pr = p.P_bf + (size_t)(b * N_SP + n) * 1536 + c0;
        float pv[6];
#pragma unroll
        for (int j = 0; j < 6; ++j) pv[j] = bf2f(pr[j]);
#pragma unroll
        for (int s = 0; s < 8; ++s) {
            float al = ee[s * 64 + n];
#pragma unroll
            for (int j = 0; j < 6; ++j) acc[s][j] = fmaf(al, pv[j], acc[s][j]);
        }
    }
    float bi[6];
#pragma unroll
    for (int j = 0; j < 6; ++j) bi[j] = p.wbih[c0 + j];
#pragma unroll
    for (int s = 0; s < 8; ++s) {
        const unsigned short* e1 = p.E1_bf + (size_t)warr[s] * 1536 + c0;
        float* go = p.gib + (size_t)(s * 64 + b) * 1536 + c0;
#pragma unroll
        for (int j = 0; j < 6; ++j) go[j] = acc[s][j] + bf2f(e1[j]) + bi[j];
    }
    __syncthreads();
    // combine -> h_w, h_all_bf
    for (int idx = tid; idx < 8 * 512; idx += 256) {
        int s = idx >> 9, c = idx & 511;
        int r = s * 64 + b;
        size_t g0 = (size_t)r * 1536 + c;
        float rr = sigm(p.gib[g0] + p.ghb[g0]);
        float zz = sigm(p.gib[g0 + 512] + p.ghb[g0 + 512]);
        float nn = tanhf(p.gib[g0 + 1024] + rr * p.ghb[g0 + 1024]);
        float h = (1.f - zz) * nn + zz * p.h_w[(size_t)r * 512 + c];
        p.h_w[(size_t)r * 512 + c] = h;
        p.h_all_bf[(size_t)((s * MW + t) * 64 + b) * 512 + c] = f2bf(h);
    }
}

__global__ __launch_bounds__(256, 2)
void word_persistent(Wp p) {
    cg::grid_group grid = cg::this_grid();
    __shared__ float smem[5120];
    __shared__ int warr[8];
    const int wg = blockIdx.x;
    for (int t = 0; t < MW; ++t) {
        // Phase A: att2 (128 tiles) + gh (384 tiles), 64x32 each, K=512
        if (wg < 128) {
            gemm_tile_64x32(p.h_w, DEC, p.adW, DEC, p.adb, p.att2, EMB,
                            (wg >> 4) * 64, (wg & 15) * 32, DEC, smem);
        } else {
            int j = wg - 128;
            gemm_tile_64x32(p.h_w, DEC, p.wWhh, DEC, p.wbhh, p.ghb, 3 * DEC,
                            (j / 48) * 64, (j % 48) * 32, DEC, smem);
        }
        grid.sync();
        // Phase B: attention + gi + combine, one wg per image
        if (wg < 64) word_phaseB(p, wg, t, smem, warr);
        grid.sync();
    }
}

extern "C" void kernel_launch(void* const* d_in, const int* in_sizes, int n_in,
                              void* d_out, int out_size, void* d_ws, size_t ws_size,
                              hipStream_t stream) {
    const float* sp   = (const float*)d_in[0];
    const int*   tw   = (const int*)d_in[1];
    const float* embW = (const float*)d_in[2];
    const float* sWih = (const float*)d_in[3];
    const float* sWhh = (const float*)d_in[4];
    const float* sbih = (const float*)d_in[5];
    const float* sbhh = (const float*)d_in[6];
    const float* pW   = (const float*)d_in[7];
    const float* pb   = (const float*)d_in[8];
    const float* stW  = (const float*)d_in[9];
    const float* stb  = (const float*)d_in[10];
    const float* aeW  = (const float*)d_in[11];
    const float* aeb  = (const float*)d_in[12];
    const float* adW  = (const float*)d_in[13];
    const float* adb  = (const float*)d_in[14];
    const float* afW  = (const float*)d_in[15];
    const float* afb  = (const float*)d_in[16];
    const float* wWih = (const float*)d_in[17];
    const float* wWhh = (const float*)d_in[18];
    const float* wbih = (const float*)d_in[19];
    const float* wbhh = (const float*)d_in[20];
    const float* fcW  = (const float*)d_in[21];
    const float* fcb  = (const float*)d_in[22];
    const float* iW   = (const float*)d_in[23];
    const float* ib   = (const float*)d_in[24];
    float* out = (float*)d_out;

    float* w = (float*)d_ws;
    float* g      = w; w += B * ENC;
    float* att1   = w; w += (size_t)B * N_SP * EMB;
    float* h_s    = w; w += B * DEC;
    float* gi_s   = w; w += B * 3 * DEC;
    float* gh_s   = w; w += B * 3 * DEC;
    float* h_sall = w; w += MS * B * DEC;
    float* xbuf   = w; w += (size_t)BW * XDIM;
    float* att2   = w; w += (size_t)BW * EMB;
    float* gib    = w; w += (size_t)BW * 3 * DEC;
    float* ghb    = w; w += (size_t)BW * 3 * DEC;
    float* h_w    = w; w += (size_t)BW * DEC;
    unsigned short* us = (unsigned short*)w;
    unsigned short* h_all_bf = us; us += (size_t)MS * MW * B * DEC;   // 10240x512
    unsigned short* fcW_bf   = us; us += (size_t)NPAD * DEC;          // 10112x512
    unsigned short* embW_bf  = us; us += (size_t)V * EMB;             // 10000x512
    unsigned short* w1_bf    = us; us += (size_t)XDIM * 512;          // 1536x512
    unsigned short* w2_bf    = us; us += (size_t)XDIM * 1024;         // 1536x1024
    unsigned short* sp_bf    = us; us += (size_t)B * N_SP * ENC;      // 3136x1024
    unsigned short* E1_bf    = us; us += (size_t)V * XDIM;            // 10000x1536
    unsigned short* P_bf     = us; us += (size_t)B * N_SP * XDIM;     // 3136x1536
    const size_t need_bytes = (size_t)((char*)us - (char*)d_ws);

    // ---- one-shot precompute ----
    mean_kernel<<<B, 256, 0, stream>>>(sp, g);
    gemm_tn<64, 64, 16, 4, 4, 0><<<dim3(512 / 64, (B * N_SP) / 64), 256, 0, stream>>>(
        sp, ENC, aeW, ENC, aeb, att1, EMB, B * N_SP, EMB, ENC);
    gemm_tn<64, 64, 16, 4, 4, 1><<<dim3(512 / 64, 1), 256, 0, stream>>>(
        g, ENC, iW, ENC, ib, h_s, DEC, B, DEC, ENC);
    gemm_tn<64, 64, 16, 4, 4, 0><<<dim3(1536 / 64, 1), 256, 0, stream>>>(
        g, ENC, sWih, ENC, sbih, gi_s, 3 * DEC, B, 3 * DEC, ENC);
    conv_w<<<1024, 256, 0, stream>>>(fcW, fcW_bf, NPAD, V);

    // ---- sentence GRU (sync-free) ----
    sent_gru<<<B, 256, 0, stream>>>(h_s, gi_s, sWhh, sbhh, h_sall, h_w);

    // ---- word loop ----
    hipError_t cerr = hipErrorUnknown;
    if (ws_size >= need_bytes) {
        conv_plain<<<2048, 256, 0, stream>>>(embW, embW_bf, (size_t)V * EMB);
        conv_plain<<<2048, 256, 0, stream>>>(sp, sp_bf, (size_t)B * N_SP * ENC);
        conv_slice<<<1024, 256, 0, stream>>>(wWih, w1_bf, 0, 512);
        conv_slice<<<1024, 256, 0, stream>>>(wWih, w2_bf, 512, 1024);
        // E1 = embW @ W1^T  [10000,1536];  P = sp @ W2^T  [3136,1536]
        gemm_bf16<<<dim3(XDIM / 128, (V + 127) / 128), 256, 0, stream>>>(
            embW_bf, w1_bf, E1_bf, V, XDIM, 512);
        gemm_bf16<<<dim3(XDIM / 128, (B * N_SP + 127) / 128), 256, 0, stream>>>(
            sp_bf, w2_bf, P_bf, B * N_SP, XDIM, 1024);

        Wp prm;
        prm.adW = adW; prm.adb = adb; prm.wWhh = wWhh; prm.wbhh = wbhh; prm.wbih = wbih;
        prm.att1 = att1; prm.afW = afW; prm.afb = afb; prm.tw = tw;
        prm.E1_bf = E1_bf; prm.P_bf = P_bf;
        prm.h_w = h_w; prm.att2 = att2; prm.ghb = ghb; prm.gib = gib;
        prm.h_all_bf = h_all_bf;
        void* kargs[] = { (void*)&prm };
        cerr = hipLaunchCooperativeKernel(
            reinterpret_cast<const void*>(&word_persistent), dim3(GRIDW), dim3(256), kargs, 0, stream);
    }
    if (cerr != hipSuccess) {
        // fallback: proven R1 discrete path
        for (int t = 0; t < MW; ++t) {
            gemm_tn<64, 64, 16, 4, 4, 0><<<dim3(512 / 64, 512 / 64), 256, 0, stream>>>(
                h_w, DEC, adW, DEC, adb, att2, EMB, BW, EMB, DEC);
            attn_kernel<<<BW, 256, 0, stream>>>(sp, att1, att2, afW, afb, embW, tw, xbuf, t);
            gemm_tn<64, 64, 16, 4, 4, 0><<<dim3(1536 / 64, 512 / 64), 256, 0, stream>>>(
                xbuf, XDIM, wWih, XDIM, wbih, gib, 3 * DEC, BW, 3 * DEC, XDIM);
            gemm_tn<64, 64, 16, 4, 4, 0><<<dim3(1536 / 64, 512 / 64), 256, 0, stream>>>(
                h_w, DEC, wWhh, DEC, wbhh, ghb, 3 * DEC, BW, 3 * DEC, DEC);
            gru_combine<<<(BW * DEC + 255) / 256, 256, 0, stream>>>(
                gib, ghb, h_w, h_w, h_all_bf, BW, t);
        }
    }

    // ---- heads ----
    policy_kernel<<<BW, 64, 0, stream>>>(h_sall, pW, pb, stW, stb, out);
    fc_mfma<<<dim3(NPAD / 128, (MS * MW * B) / 128), 256, 0, stream>>>(
        h_all_bf, fcW_bf, fcb, out + B * MS * 5 + B * MS);
}